// Round 2
// baseline (3851.144 us; speedup 1.0000x reference)
//
#include <hip/hip_runtime.h>
#include <math.h>

#define N_TOK 16384
#define H_DIM 2048
#define E_EXP 64
#define TH    128
#define NT    (H_DIM / TH)
#define RPW   8
#define RPB   32
#define WSTRIDE 132   // pad: 132*4=528 B row stride, 16B-aligned; b128 reads spread 8 words/bank (conflict-free)

// d_out layout (float32, reference return order)
#define OUT_IDX   0
#define OUT_W     (N_TOK * 2)
#define OUT_LOSS  (N_TOK * 4)
#define OUT_FRAC  (N_TOK * 4 + 1)
#define OUT_PROBS (N_TOK * 4 + 1 + E_EXP)

// ws layout (floats): [0..63] prob sums, [64..127] counts, [128] list count (int), [192..] fixup row list
#define WS_LIST_OFF 192

__device__ __forceinline__ void gload_lds16(const float* g, float* l) {
    __builtin_amdgcn_global_load_lds(
        (const __attribute__((address_space(1))) unsigned int*)g,
        (__attribute__((address_space(3))) unsigned int*)l,
        16, 0, 0);
}

__global__ void zero_ws_kernel(float* __restrict__ ws) {
    int t = threadIdx.x;
    if (t < WS_LIST_OFF) ws[t] = 0.0f;
}

__global__ __launch_bounds__(256, 2) void router_kernel(
    const float* __restrict__ x, const float* __restrict__ W,
    float* __restrict__ out, float* __restrict__ ws, int cap) {
    __shared__ float wl[E_EXP * WSTRIDE];     // 33.8 KB, single buffer (reg-double-buffered)
    __shared__ float xl[2][RPB * TH];         // 2 x 16 KB, double buffer
    const int tid  = threadIdx.x;
    const int lane = tid & 63;
    const int wid  = tid >> 6;
    const int rowBase = blockIdx.x * RPB;

    // W staging map: thread t -> expert e = t>>2, 16B group offset (t&3)*4 within each 64B chunk
    const int we  = tid >> 2;
    const int wj4 = (tid & 3) * 4;
    const float* wsrc = W + (size_t)we * H_DIM + wj4;
    float* wdst = &wl[we * WSTRIDE + wj4];

    // x staging map: per gload_lds instr i, wave stages rows wid*8 + i*2 + (lane>>5), cols (lane&31)*4
    const int xr_off = wid * 8 + (lane >> 5);
    const int xc     = (lane & 31) * 4;

    float4 wreg[8];
    float acc[RPW];
#pragma unroll
    for (int r = 0; r < RPW; ++r) acc[r] = 0.0f;

    // ---- prologue: stage tile 0 ----
#pragma unroll
    for (int j = 0; j < 8; ++j)
        wreg[j] = *(const float4*)(wsrc + j * 16);
#pragma unroll
    for (int i = 0; i < 4; ++i) {
        const float* g = x + (size_t)(rowBase + xr_off + i * 2) * H_DIM + xc;
        gload_lds16(g, &xl[0][wid * 1024 + i * 256]);
    }
#pragma unroll
    for (int j = 0; j < 8; ++j)
        *(float4*)(wdst + j * 16) = wreg[j];
    __syncthreads();   // drains vmcnt (gload_lds) + lgkm (ds_writes)

    for (int t = 0; t < NT; ++t) {
        const int h0n = (t + 1) * TH;
        if (t + 1 < NT) {
            // issue next tile's loads BEFORE compute: latency hides under ~2k cycles of FMA
#pragma unroll
            for (int j = 0; j < 8; ++j)
                wreg[j] = *(const float4*)(wsrc + h0n + j * 16);
#pragma unroll
            for (int i = 0; i < 4; ++i) {
                const float* g = x + (size_t)(rowBase + xr_off + i * 2) * H_DIM + h0n + xc;
                gload_lds16(g, &xl[(t + 1) & 1][wid * 1024 + i * 256]);
            }
        }
        // ---- compute tile t ----
        const float* xb = &xl[t & 1][wid * 8 * TH];
        const float* wb = &wl[lane * WSTRIDE];
#pragma unroll
        for (int kc = 0; kc < TH; kc += 4) {
            float4 wv = *(const float4*)(wb + kc);              // ds_read_b128, conflict-free
#pragma unroll
            for (int r = 0; r < RPW; ++r) {
                float4 xv = *(const float4*)(xb + r * TH + kc); // uniform addr -> broadcast
                acc[r] = fmaf(xv.x, wv.x, acc[r]);
                acc[r] = fmaf(xv.y, wv.y, acc[r]);
                acc[r] = fmaf(xv.z, wv.z, acc[r]);
                acc[r] = fmaf(xv.w, wv.w, acc[r]);
            }
        }
        __syncthreads();   // all reads of wl/xl done; also drains next tile's loads (already landed)
        if (t + 1 < NT) {
#pragma unroll
            for (int j = 0; j < 8; ++j)
                *(float4*)(wdst + j * 16) = wreg[j];
        }
        __syncthreads();   // wl(t+1) visible
    }

    // ---- epilogue: per-row softmax + top-2 + reductions ----
    float psum = 0.0f;
    int   pcnt = 0;
    float* outIdx = out + OUT_IDX;
    float* outW   = out + OUT_W;
    float* outP   = out + OUT_PROBS;
    int* li   = (int*)(ws + 128);
    int* list = (int*)(ws + WS_LIST_OFF);
    const int rowW = rowBase + wid * 8;

#pragma unroll 1
    for (int r = 0; r < RPW; ++r) {
        const int row = rowW + r;
        const float v = acc[r];

        float bv = v; int bi = lane;
#pragma unroll
        for (int m = 32; m >= 1; m >>= 1) {
            float ov = __shfl_xor(bv, m);
            int   oi = __shfl_xor(bi, m);
            if (ov > bv || (ov == bv && oi < bi)) { bv = ov; bi = oi; }
        }
        const float v1 = bv; const int i1 = bi;

        bv = (lane == i1) ? -__builtin_inff() : v; bi = lane;
#pragma unroll
        for (int m = 32; m >= 1; m >>= 1) {
            float ov = __shfl_xor(bv, m);
            int   oi = __shfl_xor(bi, m);
            if (ov > bv || (ov == bv && oi < bi)) { bv = ov; bi = oi; }
        }
        const float v2 = bv; const int i2 = bi;

        float t3 = (lane == i1 || lane == i2) ? -__builtin_inff() : v;
#pragma unroll
        for (int m = 32; m >= 1; m >>= 1) t3 = fmaxf(t3, __shfl_xor(t3, m));

        float ee = __expf(v - v1);
        float s = ee;
#pragma unroll
        for (int m = 32; m >= 1; m >>= 1) s += __shfl_xor(s, m);
        float prob = ee / s;
        outP[(size_t)row * E_EXP + lane] = prob;
        psum += prob;
        pcnt += (lane == i1 ? 1 : 0) + (lane == i2 ? 1 : 0);

        if (lane == 0) {
            float ew = __expf(v2 - v1);
            outIdx[row * 2]     = (float)i1;
            outIdx[row * 2 + 1] = (float)i2;
            outW[row * 2]       = 1.0f / (1.0f + ew);
            outW[row * 2 + 1]   = ew / (1.0f + ew);
            if (fminf(v1 - v2, v2 - t3) < 4e-6f) {
                int slot = atomicAdd(li, 1);
                if (slot < cap) list[slot] = row;
            }
        }
    }
    atomicAdd(&ws[lane], psum);
    atomicAdd(&ws[64 + lane], (float)pcnt);
}

// fp64 recompute of flagged near-tie rows: one block (4 waves) per row.
__global__ __launch_bounds__(256) void fixup_kernel(
    const float* __restrict__ x, const float* __restrict__ W,
    float* __restrict__ out, float* __restrict__ ws, int cap) {
    __shared__ float  xs[H_DIM];
    __shared__ double lsh[E_EXP];
    const int tid  = threadIdx.x;
    const int lane = tid & 63;
    const int wid  = tid >> 6;
    const int* li   = (const int*)(ws + 128);
    const int* list = (const int*)(ws + WS_LIST_OFF);
    int cnt = *li;
    if (cnt > cap) cnt = cap;

    for (int j = blockIdx.x; j < cnt; j += gridDim.x) {
        const int row = list[j];
        const float* xr = x + (size_t)row * H_DIM;
#pragma unroll
        for (int i = 0; i < 2; ++i)
            *(float4*)&xs[i * 1024 + tid * 4] = *(const float4*)(xr + i * 1024 + tid * 4);
        __syncthreads();

#pragma unroll 1
        for (int ee = 0; ee < 16; ++ee) {
            const int e = wid * 16 + ee;
            const float* wr = W + (size_t)e * H_DIM;
            double s0 = 0.0, s1 = 0.0, s2 = 0.0, s3 = 0.0;
#pragma unroll
            for (int i = 0; i < H_DIM; i += 256) {
                s0 += (double)xs[i + lane]       * (double)wr[i + lane];
                s1 += (double)xs[i + lane + 64]  * (double)wr[i + lane + 64];
                s2 += (double)xs[i + lane + 128] * (double)wr[i + lane + 128];
                s3 += (double)xs[i + lane + 192] * (double)wr[i + lane + 192];
            }
            double sd = (s0 + s1) + (s2 + s3);
#pragma unroll
            for (int m = 32; m >= 1; m >>= 1) sd += __shfl_xor(sd, m);
            if (lane == 0) lsh[e] = sd;
        }
        __syncthreads();

        if (wid == 0) {
            const double v = lsh[lane];
            double bv = v; int bi = lane;
#pragma unroll
            for (int m = 32; m >= 1; m >>= 1) {
                double ov = __shfl_xor(bv, m);
                int    oi = __shfl_xor(bi, m);
                if (ov > bv || (ov == bv && oi < bi)) { bv = ov; bi = oi; }
            }
            const double v1 = bv; const int i1 = bi;
            bv = (lane == i1) ? -1.0e300 : v; bi = lane;
#pragma unroll
            for (int m = 32; m >= 1; m >>= 1) {
                double ov = __shfl_xor(bv, m);
                int    oi = __shfl_xor(bi, m);
                if (ov > bv || (ov == bv && oi < bi)) { bv = ov; bi = oi; }
            }
            const double v2 = bv; const int i2 = bi;
            if (lane == 0) {
                double ew = exp(v2 - v1);
                out[OUT_IDX + row * 2]     = (float)i1;
                out[OUT_IDX + row * 2 + 1] = (float)i2;
                out[OUT_W + row * 2]       = (float)(1.0 / (1.0 + ew));
                out[OUT_W + row * 2 + 1]   = (float)(ew / (1.0 + ew));
            }
        }
        __syncthreads();
    }
}

__global__ void finalize_kernel(float* __restrict__ out, const float* __restrict__ ws) {
    const int lane = threadIdx.x;  // 64 threads
    float f = ws[64 + lane] * (1.0f / (float)N_TOK);
    float p = ws[lane]      * (1.0f / (float)N_TOK);
    out[OUT_FRAC + lane] = f;
    float prod = f * p;
#pragma unroll
    for (int m = 32; m >= 1; m >>= 1) prod += __shfl_xor(prod, m);
    if (lane == 0) out[OUT_LOSS] = (float)E_EXP * prod;
}

extern "C" void kernel_launch(void* const* d_in, const int* in_sizes, int n_in,
                              void* d_out, int out_size, void* d_ws, size_t ws_size,
                              hipStream_t stream) {
    const float* x = (const float*)d_in[0];
    const float* W = (const float*)d_in[1];
    float* out = (float*)d_out;
    float* ws  = (float*)d_ws;

    size_t ws_floats = ws_size / 4;
    int cap = 0;
    if (ws_floats > WS_LIST_OFF) {
        size_t c = ws_floats - WS_LIST_OFF;
        cap = (c > (size_t)N_TOK) ? N_TOK : (int)c;
    }

    zero_ws_kernel<<<1, 256, 0, stream>>>(ws);
    router_kernel<<<N_TOK / RPB, 256, 0, stream>>>(x, W, out, ws, cap);
    fixup_kernel<<<256, 256, 0, stream>>>(x, W, out, ws, cap);
    finalize_kernel<<<1, 64, 0, stream>>>(out, ws);
}

// Round 4
// 1145.898 us; speedup vs baseline: 3.3608x; 3.3608x over previous
//
#include <hip/hip_runtime.h>
#include <math.h>

#define N_TOK 16384
#define H_DIM 2048
#define E_EXP 64
#define RPB   16                 // rows per block
#define NKQ   (H_DIM / 4)        // 512 float4 k-quads per row

// d_out layout (float32, reference return order)
#define OUT_IDX   0
#define OUT_W     (N_TOK * 2)
#define OUT_LOSS  (N_TOK * 4)
#define OUT_FRAC  (N_TOK * 4 + 1)
#define OUT_PROBS (N_TOK * 4 + 1 + E_EXP)

// ws layout (floats): [0..63] prob sums, [64..127] counts, [128] list count (int), [192..] fixup row list
#define WS_LIST_OFF 192

__global__ void zero_ws_kernel(float* __restrict__ ws) {
    int t = threadIdx.x;
    if (t < WS_LIST_OFF) ws[t] = 0.0f;
}

#define FMA4(acc, xv, wv)              \
    acc = fmaf(xv.x, wv.x, acc);       \
    acc = fmaf(xv.y, wv.y, acc);       \
    acc = fmaf(xv.z, wv.z, acc);       \
    acc = fmaf(xv.w, wv.w, acc);

// lane = (e_sub = lane>>2 in [0,16), r_sub = lane&3). Wave w covers experts [16w,16w+16),
// rows 4j + r_sub (j=0..3). No LDS / no barriers in the K-loop; x broadcast via L1.
__global__ __launch_bounds__(256, 4) void router_kernel(
    const float* __restrict__ x, const float* __restrict__ W,
    float* __restrict__ out, float* __restrict__ ws, int cap) {
    __shared__ float lg[RPB * 68];   // logits tile, stride 68 (conflict-light)
    const int tid  = threadIdx.x;
    const int lane = tid & 63;
    const int wid  = tid >> 6;
    const int e_sub = lane >> 2;
    const int r_sub = lane & 3;
    const int e = wid * 16 + e_sub;
    const int rowBase = blockIdx.x * RPB;

    const float4* xq0 = (const float4*)(x + (size_t)(rowBase + 0  + r_sub) * H_DIM);
    const float4* xq1 = (const float4*)(x + (size_t)(rowBase + 4  + r_sub) * H_DIM);
    const float4* xq2 = (const float4*)(x + (size_t)(rowBase + 8  + r_sub) * H_DIM);
    const float4* xq3 = (const float4*)(x + (size_t)(rowBase + 12 + r_sub) * H_DIM);
    const float4* wq  = (const float4*)(W + (size_t)e * H_DIM);

    float a0 = 0.f, a1 = 0.f, a2 = 0.f, a3 = 0.f;

    // 2-slot software pipeline, named registers (no runtime-indexed arrays)
    float4 xA0 = xq0[0], xA1 = xq1[0], xA2 = xq2[0], xA3 = xq3[0], wA = wq[0];
    float4 xB0 = xq0[1], xB1 = xq1[1], xB2 = xq2[1], xB3 = xq3[1], wB = wq[1];

#pragma unroll 2
    for (int kqp = 0; kqp < NKQ - 2; kqp += 2) {
        // compute k-quad kqp (slot A), then refill A with kqp+2
        FMA4(a0, xA0, wA) FMA4(a1, xA1, wA) FMA4(a2, xA2, wA) FMA4(a3, xA3, wA)
        xA0 = xq0[kqp + 2]; xA1 = xq1[kqp + 2]; xA2 = xq2[kqp + 2]; xA3 = xq3[kqp + 2];
        wA  = wq[kqp + 2];
        // compute k-quad kqp+1 (slot B), then refill B with kqp+3
        FMA4(a0, xB0, wB) FMA4(a1, xB1, wB) FMA4(a2, xB2, wB) FMA4(a3, xB3, wB)
        xB0 = xq0[kqp + 3]; xB1 = xq1[kqp + 3]; xB2 = xq2[kqp + 3]; xB3 = xq3[kqp + 3];
        wB  = wq[kqp + 3];
    }
    // tail: k-quads NKQ-2 (A) and NKQ-1 (B)
    FMA4(a0, xA0, wA) FMA4(a1, xA1, wA) FMA4(a2, xA2, wA) FMA4(a3, xA3, wA)
    FMA4(a0, xB0, wB) FMA4(a1, xB1, wB) FMA4(a2, xB2, wB) FMA4(a3, xB3, wB)

    // publish logits to LDS: row 4j + r_sub, expert e
    lg[(0  + r_sub) * 68 + e] = a0;
    lg[(4  + r_sub) * 68 + e] = a1;
    lg[(8  + r_sub) * 68 + e] = a2;
    lg[(12 + r_sub) * 68 + e] = a3;
    __syncthreads();

    // ---- epilogue: wave w handles rows [4w, 4w+4); lane = expert ----
    float psum = 0.0f;
    int   pcnt = 0;
    float* outIdx = out + OUT_IDX;
    float* outW   = out + OUT_W;
    float* outP   = out + OUT_PROBS;
    int* li   = (int*)(ws + 128);
    int* list = (int*)(ws + WS_LIST_OFF);

#pragma unroll 1
    for (int rr = 0; rr < 4; ++rr) {
        const int rloc = wid * 4 + rr;
        const int row  = rowBase + rloc;
        const float v  = lg[rloc * 68 + lane];

        // top-1 (value, lowest index on tie)
        float bv = v; int bi = lane;
#pragma unroll
        for (int m = 32; m >= 1; m >>= 1) {
            float ov = __shfl_xor(bv, m);
            int   oi = __shfl_xor(bi, m);
            if (ov > bv || (ov == bv && oi < bi)) { bv = ov; bi = oi; }
        }
        const float v1 = bv; const int i1 = bi;

        // top-2
        bv = (lane == i1) ? -__builtin_inff() : v; bi = lane;
#pragma unroll
        for (int m = 32; m >= 1; m >>= 1) {
            float ov = __shfl_xor(bv, m);
            int   oi = __shfl_xor(bi, m);
            if (ov > bv || (ov == bv && oi < bi)) { bv = ov; bi = oi; }
        }
        const float v2 = bv; const int i2 = bi;

        // third-best value (selection-boundary gap)
        float t3 = (lane == i1 || lane == i2) ? -__builtin_inff() : v;
#pragma unroll
        for (int m = 32; m >= 1; m >>= 1) t3 = fmaxf(t3, __shfl_xor(t3, m));

        // full softmax over 64 experts
        float ee = __expf(v - v1);
        float s = ee;
#pragma unroll
        for (int m = 32; m >= 1; m >>= 1) s += __shfl_xor(s, m);
        float prob = ee / s;
        outP[(size_t)row * E_EXP + lane] = prob;
        psum += prob;
        pcnt += (lane == i1 ? 1 : 0) + (lane == i2 ? 1 : 0);

        if (lane == 0) {
            float ew = __expf(v2 - v1);
            outIdx[row * 2]     = (float)i1;
            outIdx[row * 2 + 1] = (float)i2;
            outW[row * 2]       = 1.0f / (1.0f + ew);
            outW[row * 2 + 1]   = ew / (1.0f + ew);
            if (fminf(v1 - v2, v2 - t3) < 4e-6f) {
                int slot = atomicAdd(li, 1);
                if (slot < cap) list[slot] = row;
            }
        }
    }
    atomicAdd(&ws[lane], psum);
    atomicAdd(&ws[64 + lane], (float)pcnt);
}

// fp64 recompute of flagged near-tie rows: one 256-thread block per row;
// waves split experts (16 each), lanes split H with float4 coalesced loads.
__global__ __launch_bounds__(256) void fixup_kernel(
    const float* __restrict__ x, const float* __restrict__ W,
    float* __restrict__ out, float* __restrict__ ws, int cap) {
    __shared__ float  xs[H_DIM];
    __shared__ double lsh[E_EXP];
    const int tid  = threadIdx.x;
    const int lane = tid & 63;
    const int wid  = tid >> 6;
    const int* li   = (const int*)(ws + 128);
    const int* list = (const int*)(ws + WS_LIST_OFF);
    int cnt = *li;
    if (cnt > cap) cnt = cap;

    for (int j = blockIdx.x; j < cnt; j += gridDim.x) {
        const int row = list[j];
        const float* xr = x + (size_t)row * H_DIM;
        *(float4*)&xs[tid * 4]        = *(const float4*)(xr + tid * 4);
        *(float4*)&xs[1024 + tid * 4] = *(const float4*)(xr + 1024 + tid * 4);
        __syncthreads();

#pragma unroll 1
        for (int ee = 0; ee < 16; ++ee) {
            const int e = wid * 16 + ee;
            const float4* wr4 = (const float4*)(W + (size_t)e * H_DIM);
            double s0 = 0.0, s1 = 0.0;
#pragma unroll
            for (int i = 0; i < 8; ++i) {
                float4 wv = wr4[lane + 64 * i];
                float4 xv = *(const float4*)&xs[(lane + 64 * i) * 4];
                s0 += (double)xv.x * (double)wv.x + (double)xv.z * (double)wv.z;
                s1 += (double)xv.y * (double)wv.y + (double)xv.w * (double)wv.w;
            }
            double sd = s0 + s1;
#pragma unroll
            for (int m = 32; m >= 1; m >>= 1) sd += __shfl_xor(sd, m);
            if (lane == 0) lsh[e] = sd;
        }
        __syncthreads();

        if (wid == 0) {
            const double v = lsh[lane];
            double bv = v; int bi = lane;
#pragma unroll
            for (int m = 32; m >= 1; m >>= 1) {
                double ov = __shfl_xor(bv, m);
                int    oi = __shfl_xor(bi, m);
                if (ov > bv || (ov == bv && oi < bi)) { bv = ov; bi = oi; }
            }
            const double v1 = bv; const int i1 = bi;
            bv = (lane == i1) ? -1.0e300 : v; bi = lane;
#pragma unroll
            for (int m = 32; m >= 1; m >>= 1) {
                double ov = __shfl_xor(bv, m);
                int    oi = __shfl_xor(bi, m);
                if (ov > bv || (ov == bv && oi < bi)) { bv = ov; bi = oi; }
            }
            const double v2 = bv; const int i2 = bi;
            if (lane == 0) {
                double ew = exp(v2 - v1);
                out[OUT_IDX + row * 2]     = (float)i1;
                out[OUT_IDX + row * 2 + 1] = (float)i2;
                out[OUT_W + row * 2]       = (float)(1.0 / (1.0 + ew));
                out[OUT_W + row * 2 + 1]   = (float)(ew / (1.0 + ew));
            }
        }
        __syncthreads();
    }
}

__global__ void finalize_kernel(float* __restrict__ out, const float* __restrict__ ws) {
    const int lane = threadIdx.x;  // 64 threads
    float f = ws[64 + lane] * (1.0f / (float)N_TOK);
    float p = ws[lane]      * (1.0f / (float)N_TOK);
    out[OUT_FRAC + lane] = f;
    float prod = f * p;
#pragma unroll
    for (int m = 32; m >= 1; m >>= 1) prod += __shfl_xor(prod, m);
    if (lane == 0) out[OUT_LOSS] = (float)E_EXP * prod;
}

extern "C" void kernel_launch(void* const* d_in, const int* in_sizes, int n_in,
                              void* d_out, int out_size, void* d_ws, size_t ws_size,
                              hipStream_t stream) {
    const float* x = (const float*)d_in[0];
    const float* W = (const float*)d_in[1];
    float* out = (float*)d_out;
    float* ws  = (float*)d_ws;

    size_t ws_floats = ws_size / 4;
    int cap = 0;
    if (ws_floats > WS_LIST_OFF) {
        size_t c = ws_floats - WS_LIST_OFF;
        cap = (c > (size_t)N_TOK) ? N_TOK : (int)c;
    }

    zero_ws_kernel<<<1, 256, 0, stream>>>(ws);
    router_kernel<<<N_TOK / RPB, 256, 0, stream>>>(x, W, out, ws, cap);
    fixup_kernel<<<512, 256, 0, stream>>>(x, W, out, ws, cap);
    finalize_kernel<<<1, 64, 0, stream>>>(out, ws);
}

// Round 5
// 330.063 us; speedup vs baseline: 11.6679x; 3.4718x over previous
//
#include <hip/hip_runtime.h>
#include <math.h>

#define N_TOK 16384
#define H_DIM 2048
#define E_EXP 64
#define RPB   32                 // rows per block
#define KC    128                // k-chunk (floats)
#define NCH   (H_DIM / KC)       // 16 chunks
#define XSTR  132                // LDS row stride (x), multiple of 4 for b128 alignment
#define WSTR  132                // LDS row stride (w)

// d_out layout (float32, reference return order)
#define OUT_IDX   0
#define OUT_W     (N_TOK * 2)
#define OUT_LOSS  (N_TOK * 4)
#define OUT_FRAC  (N_TOK * 4 + 1)
#define OUT_PROBS (N_TOK * 4 + 1 + E_EXP)

// ws layout (floats): [0..63] prob sums, [64..127] counts, [128] list count (int), [192..] fixup row list
#define WS_LIST_OFF 192

__global__ void zero_ws_kernel(float* __restrict__ ws) {
    int t = threadIdx.x;
    if (t < WS_LIST_OFF) ws[t] = 0.0f;
}

#define FMA4(acc, xv, wv)              \
    acc = fmaf(xv.x, wv.x, acc);       \
    acc = fmaf(xv.y, wv.y, acc);       \
    acc = fmaf(xv.z, wv.z, acc);       \
    acc = fmaf(xv.w, wv.w, acc);

// Staging map: thread t -> quad q = t&31, row-group r0 = t>>5 (0..7).
// x rows r0+8j (j=0..3), W rows r0+8j (j=0..7); per wave instr: 2 rows x 512B contiguous.
#define STAGE_LOAD(c) do {                                  \
    const float* xp = xg + (c) * KC;                        \
    xs0 = *(const float4*)(xp + 0  * 8 * H_DIM);            \
    xs1 = *(const float4*)(xp + 1  * 8 * H_DIM);            \
    xs2 = *(const float4*)(xp + 2  * 8 * H_DIM);            \
    xs3 = *(const float4*)(xp + 3  * 8 * H_DIM);            \
    const float* wp = wg + (c) * KC;                        \
    wr0 = *(const float4*)(wp + 0 * 8 * H_DIM);             \
    wr1 = *(const float4*)(wp + 1 * 8 * H_DIM);             \
    wr2 = *(const float4*)(wp + 2 * 8 * H_DIM);             \
    wr3 = *(const float4*)(wp + 3 * 8 * H_DIM);             \
    wr4 = *(const float4*)(wp + 4 * 8 * H_DIM);             \
    wr5 = *(const float4*)(wp + 5 * 8 * H_DIM);             \
    wr6 = *(const float4*)(wp + 6 * 8 * H_DIM);             \
    wr7 = *(const float4*)(wp + 7 * 8 * H_DIM);             \
} while (0)

#define STAGE_WRITE() do {                                  \
    *(float4*)&xl[(r0 + 0 ) * XSTR + 4 * q] = xs0;          \
    *(float4*)&xl[(r0 + 8 ) * XSTR + 4 * q] = xs1;          \
    *(float4*)&xl[(r0 + 16) * XSTR + 4 * q] = xs2;          \
    *(float4*)&xl[(r0 + 24) * XSTR + 4 * q] = xs3;          \
    *(float4*)&wl[(r0 + 0 ) * WSTR + 4 * q] = wr0;          \
    *(float4*)&wl[(r0 + 8 ) * WSTR + 4 * q] = wr1;          \
    *(float4*)&wl[(r0 + 16) * WSTR + 4 * q] = wr2;          \
    *(float4*)&wl[(r0 + 24) * WSTR + 4 * q] = wr3;          \
    *(float4*)&wl[(r0 + 32) * WSTR + 4 * q] = wr4;          \
    *(float4*)&wl[(r0 + 40) * WSTR + 4 * q] = wr5;          \
    *(float4*)&wl[(r0 + 48) * WSTR + 4 * q] = wr6;          \
    *(float4*)&wl[(r0 + 56) * WSTR + 4 * q] = wr7;          \
} while (0)

// Compute layout (round-4, proven): lane = (e_sub = lane>>2 in [0,16), r_sub = lane&3).
// Wave w covers experts [16w,16w+16) x rows {r_sub + 4j, j=0..7} (32 rows shared by block).
__global__ __launch_bounds__(256, 2) void router_kernel(
    const float* __restrict__ x, const float* __restrict__ W,
    float* __restrict__ out, float* __restrict__ ws, int cap) {
    __shared__ float xl[RPB * XSTR];      // 16.9 KB
    __shared__ float wl[E_EXP * WSTR];    // 33.8 KB
    __shared__ float lg[RPB * 68];        // 8.7 KB logits tile
    const int tid  = threadIdx.x;
    const int lane = tid & 63;
    const int wid  = tid >> 6;
    const int e_sub = lane >> 2;
    const int r_sub = lane & 3;
    const int e = wid * 16 + e_sub;
    const int rowBase = blockIdx.x * RPB;

    const int q  = tid & 31;
    const int r0 = tid >> 5;
    const float* xg = x + (size_t)(rowBase + r0) * H_DIM + 4 * q;
    const float* wg = W + (size_t)r0 * H_DIM + 4 * q;

    float4 xs0, xs1, xs2, xs3;
    float4 wr0, wr1, wr2, wr3, wr4, wr5, wr6, wr7;

    float acc[8];
#pragma unroll
    for (int j = 0; j < 8; ++j) acc[j] = 0.0f;

    // prologue: stage chunk 0
    STAGE_LOAD(0);
    STAGE_WRITE();
    __syncthreads();

    const float* wrow = &wl[e * WSTR];
    const float* xrow = &xl[r_sub * XSTR];

    for (int c = 0; c < NCH; ++c) {
        if (c + 1 < NCH) STAGE_LOAD(c + 1);   // issue early: latency hides under compute
#pragma unroll 4
        for (int kq = 0; kq < KC / 4; ++kq) {
            float4 wv = *(const float4*)(wrow + 4 * kq);       // 16 addrs/wave, 2/bank-group
#pragma unroll
            for (int j = 0; j < 8; ++j) {
                float4 xv = *(const float4*)(xrow + (4 * j) * XSTR + 4 * kq); // 4 addrs, bcast
                FMA4(acc[j], xv, wv)
            }
        }
        __syncthreads();                       // all reads of chunk c done
        if (c + 1 < NCH) STAGE_WRITE();        // vmcnt drains here, after compute
        __syncthreads();                       // chunk c+1 visible
    }

    // publish logits: acc[j] is row r_sub + 4j, expert e
#pragma unroll
    for (int j = 0; j < 8; ++j)
        lg[(r_sub + 4 * j) * 68 + e] = acc[j];
    __syncthreads();

    // ---- epilogue: wave w handles rows [8w, 8w+8); lane = expert ----
    float psum = 0.0f;
    int   pcnt = 0;
    float* outIdx = out + OUT_IDX;
    float* outW   = out + OUT_W;
    float* outP   = out + OUT_PROBS;
    int* li   = (int*)(ws + 128);
    int* list = (int*)(ws + WS_LIST_OFF);

#pragma unroll 1
    for (int rr = 0; rr < 8; ++rr) {
        const int rloc = wid * 8 + rr;
        const int row  = rowBase + rloc;
        const float v  = lg[rloc * 68 + lane];

        // top-1 (value, lowest index on tie)
        float bv = v; int bi = lane;
#pragma unroll
        for (int m = 32; m >= 1; m >>= 1) {
            float ov = __shfl_xor(bv, m);
            int   oi = __shfl_xor(bi, m);
            if (ov > bv || (ov == bv && oi < bi)) { bv = ov; bi = oi; }
        }
        const float v1 = bv; const int i1 = bi;

        // top-2
        bv = (lane == i1) ? -__builtin_inff() : v; bi = lane;
#pragma unroll
        for (int m = 32; m >= 1; m >>= 1) {
            float ov = __shfl_xor(bv, m);
            int   oi = __shfl_xor(bi, m);
            if (ov > bv || (ov == bv && oi < bi)) { bv = ov; bi = oi; }
        }
        const float v2 = bv; const int i2 = bi;

        // third-best value (selection-boundary gap)
        float t3 = (lane == i1 || lane == i2) ? -__builtin_inff() : v;
#pragma unroll
        for (int m = 32; m >= 1; m >>= 1) t3 = fmaxf(t3, __shfl_xor(t3, m));

        // full softmax over 64 experts
        float ee = __expf(v - v1);
        float s = ee;
#pragma unroll
        for (int m = 32; m >= 1; m >>= 1) s += __shfl_xor(s, m);
        float prob = ee / s;
        outP[(size_t)row * E_EXP + lane] = prob;
        psum += prob;
        pcnt += (lane == i1 ? 1 : 0) + (lane == i2 ? 1 : 0);

        if (lane == 0) {
            float ew = __expf(v2 - v1);
            outIdx[row * 2]     = (float)i1;
            outIdx[row * 2 + 1] = (float)i2;
            outW[row * 2]       = 1.0f / (1.0f + ew);
            outW[row * 2 + 1]   = ew / (1.0f + ew);
            if (fminf(v1 - v2, v2 - t3) < 4e-6f) {
                int slot = atomicAdd(li, 1);
                if (slot < cap) list[slot] = row;
            }
        }
    }
    atomicAdd(&ws[lane], psum);
    atomicAdd(&ws[64 + lane], (float)pcnt);
}

// fp64 recompute of flagged near-tie rows: one 256-thread block per row;
// waves split experts (16 each), lanes split H with float4 coalesced loads.
__global__ __launch_bounds__(256) void fixup_kernel(
    const float* __restrict__ x, const float* __restrict__ W,
    float* __restrict__ out, float* __restrict__ ws, int cap) {
    __shared__ float  xs[H_DIM];
    __shared__ double lsh[E_EXP];
    const int tid  = threadIdx.x;
    const int lane = tid & 63;
    const int wid  = tid >> 6;
    const int* li   = (const int*)(ws + 128);
    const int* list = (const int*)(ws + WS_LIST_OFF);
    int cnt = *li;
    if (cnt > cap) cnt = cap;

    for (int j = blockIdx.x; j < cnt; j += gridDim.x) {
        const int row = list[j];
        const float* xr = x + (size_t)row * H_DIM;
        *(float4*)&xs[tid * 4]        = *(const float4*)(xr + tid * 4);
        *(float4*)&xs[1024 + tid * 4] = *(const float4*)(xr + 1024 + tid * 4);
        __syncthreads();

#pragma unroll 1
        for (int ee = 0; ee < 16; ++ee) {
            const int e = wid * 16 + ee;
            const float4* wr4 = (const float4*)(W + (size_t)e * H_DIM);
            double s0 = 0.0, s1 = 0.0;
#pragma unroll
            for (int i = 0; i < 8; ++i) {
                float4 wv = wr4[lane + 64 * i];
                float4 xv = *(const float4*)&xs[(lane + 64 * i) * 4];
                s0 += (double)xv.x * (double)wv.x + (double)xv.z * (double)wv.z;
                s1 += (double)xv.y * (double)wv.y + (double)xv.w * (double)wv.w;
            }
            double sd = s0 + s1;
#pragma unroll
            for (int m = 32; m >= 1; m >>= 1) sd += __shfl_xor(sd, m);
            if (lane == 0) lsh[e] = sd;
        }
        __syncthreads();

        if (wid == 0) {
            const double v = lsh[lane];
            double bv = v; int bi = lane;
#pragma unroll
            for (int m = 32; m >= 1; m >>= 1) {
                double ov = __shfl_xor(bv, m);
                int    oi = __shfl_xor(bi, m);
                if (ov > bv || (ov == bv && oi < bi)) { bv = ov; bi = oi; }
            }
            const double v1 = bv; const int i1 = bi;
            bv = (lane == i1) ? -1.0e300 : v; bi = lane;
#pragma unroll
            for (int m = 32; m >= 1; m >>= 1) {
                double ov = __shfl_xor(bv, m);
                int    oi = __shfl_xor(bi, m);
                if (ov > bv || (ov == bv && oi < bi)) { bv = ov; bi = oi; }
            }
            const double v2 = bv; const int i2 = bi;
            if (lane == 0) {
                double ew = exp(v2 - v1);
                out[OUT_IDX + row * 2]     = (float)i1;
                out[OUT_IDX + row * 2 + 1] = (float)i2;
                out[OUT_W + row * 2]       = (float)(1.0 / (1.0 + ew));
                out[OUT_W + row * 2 + 1]   = (float)(ew / (1.0 + ew));
            }
        }
        __syncthreads();
    }
}

__global__ void finalize_kernel(float* __restrict__ out, const float* __restrict__ ws) {
    const int lane = threadIdx.x;  // 64 threads
    float f = ws[64 + lane] * (1.0f / (float)N_TOK);
    float p = ws[lane]      * (1.0f / (float)N_TOK);
    out[OUT_FRAC + lane] = f;
    float prod = f * p;
#pragma unroll
    for (int m = 32; m >= 1; m >>= 1) prod += __shfl_xor(prod, m);
    if (lane == 0) out[OUT_LOSS] = (float)E_EXP * prod;
}

extern "C" void kernel_launch(void* const* d_in, const int* in_sizes, int n_in,
                              void* d_out, int out_size, void* d_ws, size_t ws_size,
                              hipStream_t stream) {
    const float* x = (const float*)d_in[0];
    const float* W = (const float*)d_in[1];
    float* out = (float*)d_out;
    float* ws  = (float*)d_ws;

    size_t ws_floats = ws_size / 4;
    int cap = 0;
    if (ws_floats > WS_LIST_OFF) {
        size_t c = ws_floats - WS_LIST_OFF;
        cap = (c > (size_t)N_TOK) ? N_TOK : (int)c;
    }

    zero_ws_kernel<<<1, 256, 0, stream>>>(ws);
    router_kernel<<<N_TOK / RPB, 256, 0, stream>>>(x, W, out, ws, cap);
    fixup_kernel<<<512, 256, 0, stream>>>(x, W, out, ws, cap);
    finalize_kernel<<<1, 64, 0, stream>>>(out, ws);
}